// Round 17
// baseline (92.078 us; speedup 1.0000x reference)
//
#include <hip/hip_runtime.h>
#include <hip/hip_bf16.h>
#include <math.h>

#define BATCH 16
#define CT    256   // total input channels = R*Cin
#define HW    64
#define OCH   64    // O
#define NK    4     // K kernels in bank
#define HP    66    // padded spatial
#define NPIX  4356  // 66*66

typedef __attribute__((ext_vector_type(4)))  float  f32x4;
typedef __attribute__((ext_vector_type(8)))  short  s16x8;
typedef __attribute__((ext_vector_type(4)))  unsigned short u16x4;

#define GLOBAL_AS __attribute__((address_space(1)))
#define LDS_AS    __attribute__((address_space(3)))

// rot90 source-index tables: w[s] = base[rotsrc[k][s]]
__device__ __constant__ int c_rotsrc[4][9] = {
    {0,1,2,3,4,5,6,7,8},
    {2,5,8,1,4,7,0,3,6},
    {8,7,6,5,4,3,2,1,0},
    {6,3,0,7,4,1,8,5,2}
};

static __device__ inline unsigned short f2bf(float f) {
    union { __hip_bfloat16 h; unsigned short u; } cv;
    cv.h = __float2bfloat16(f);
    return cv.u;
}

// ---------------- kernel 1: fused transpose+pad+pool-partials ----------------
// xTg2[b][ch(8)][pix(4356)][32ci] bf16, zero borders; partial[b][r][ci] sums.
__global__ __launch_bounds__(256) void xpose_pool(const float* __restrict__ x,
                                                  unsigned short* __restrict__ xTg,
                                                  float* __restrict__ partial) {
    const int ci0 = blockIdx.x * 64;
    const int ch0 = ci0 >> 5;          // first of 2 chunks
    const int pr  = blockIdx.y;        // padded row 0..65
    const int b   = blockIdx.z;
    const int t   = threadIdx.x;

    if (pr == 0 || pr == HP-1) {       // zero top/bottom padded rows
        for (int u = t; u < 528; u += 256) {   // 2ch x 66px x 4 quads
            int chl = (u >= 264) ? 1 : 0;
            int rem = u - chl*264;
            int c = rem >> 2, q = rem & 3;
            *(s16x8*)(xTg + (((size_t)(b*8 + ch0 + chl))*NPIX + pr*HP + c)*32 + q*8) =
                (s16x8)(short)0;
        }
        return;
    }
    const int r = pr - 1;

    __shared__ unsigned short tile[64][70];
    const int cilH = t >> 4;        // 0..15
    const int c0   = (t & 15) * 4;  // col group
    #pragma unroll
    for (int i = 0; i < 4; ++i) {
        int cil = cilH + i*16;
        f32x4 v = *(const f32x4*)(x + (((size_t)(b*CT + ci0 + cil))*HW + r)*HW + c0);
        tile[cil][c0+0] = f2bf(v[0]);
        tile[cil][c0+1] = f2bf(v[1]);
        tile[cil][c0+2] = f2bf(v[2]);
        tile[cil][c0+3] = f2bf(v[3]);
        float s = v[0] + v[1] + v[2] + v[3];
        s += __shfl_xor(s, 1, 16);
        s += __shfl_xor(s, 2, 16);
        s += __shfl_xor(s, 4, 16);
        s += __shfl_xor(s, 8, 16);
        if ((t & 15) == 0)
            partial[((size_t)(b*HW) + r)*CT + ci0 + cil] = s;
    }
    __syncthreads();

    if (t < 16) {                      // zero left/right border pixels
        int side = t >> 3, r8 = t & 7;
        int chl = r8 >> 2, q = r8 & 3;
        *(s16x8*)(xTg + (((size_t)(b*8 + ch0 + chl))*NPIX + pr*HP + side*(HP-1))*32 + q*8) =
            (s16x8)(short)0;
    }
    // transposed interior writes: ci-innermost, fully coalesced 64B runs
    #pragma unroll
    for (int i = 0; i < 4; ++i) {
        const int chl = i >> 1;
        const int c   = (i & 1)*32 + (t >> 3);   // 0..63
        const int q   = t & 7;                   // ci quad within chunk
        u16x4 w;
        w[0] = tile[chl*32 + q*4 + 0][c];
        w[1] = tile[chl*32 + q*4 + 1][c];
        w[2] = tile[chl*32 + q*4 + 2][c];
        w[3] = tile[chl*32 + q*4 + 3][c];
        *(u16x4*)(xTg + (((size_t)(b*8 + ch0 + chl))*NPIX + pr*HP + c + 1)*32 + q*4) = w;
    }
}

// ------- kernel 2: fused (coeff reduce+FC+sigmoid) | (bank rotation) --------
__global__ __launch_bounds__(256) void coeff_bankrot_kernel(
        const float* __restrict__ partial,
        const float* __restrict__ fc_w,
        const float* __restrict__ fc_b,
        const float* __restrict__ bank,
        float* __restrict__ coeffs,
        float* __restrict__ P) {
    const int blk = blockIdx.x;
    const int t   = threadIdx.x;

    if (blk < BATCH) {                 // ---- coeff part ----
        const int b = blk;
        const float* pp = partial + (size_t)b*HW*CT + t;
        float s = 0.f;
        #pragma unroll 8
        for (int r = 0; r < HW; ++r) s += pp[(size_t)r*CT];
        __shared__ float pool[CT];
        pool[t] = s * (1.f / (HW*HW));
        __syncthreads();
        const int w = t >> 6, l = t & 63;
        float d = 0.f;
        for (int c = l; c < CT; c += 64) d += pool[c] * fc_w[w*CT + c];
        for (int off = 32; off; off >>= 1) d += __shfl_down(d, off, 64);
        if (l == 0)
            coeffs[b*NK + w] = 1.f / (1.f + expf(-(d + fc_b[w])));
        return;
    }

    // ---- bankrot part: idx over 4*64*64 ----
    const int idx = (blk - BATCH) * 256 + t;
    const int o = idx & 63;
    const int c = (idx >> 6) & 63;
    const int k = idx >> 12;
    const float* bp = bank + ((size_t)((k*OCH + o)*64 + c))*9;
    float v[9];
    #pragma unroll
    for (int s = 0; s < 9; ++s) v[s] = bp[s];
    #pragma unroll
    for (int rr = 0; rr < 4; ++rr)
        #pragma unroll
        for (int s = 0; s < 9; ++s)
            P[(size_t)(((k*4 + rr)*9 + s))*4096 + c*64 + o] = v[c_rotsrc[rr][s]];
}

// ---------------- kernel 3: coalesced mix -> bf16 weights ----------------
// W[b][s][cig][co][8ci]; grid (32 cig, 9 s) x 256 threads (co).
__global__ __launch_bounds__(256) void wbuild_kernel(const float* __restrict__ coeffs,
                                                     const float* __restrict__ P,
                                                     unsigned short* __restrict__ Wb) {
    const int cig = blockIdx.x;
    const int s   = blockIdx.y;
    const int co  = threadIdx.x;
    const int ro  = co >> 6;
    const int o   = co & 63;
    const int ri  = cig >> 3;
    const int rr  = (ro - ri) & 3;
    const int c8  = (cig & 7) * 8;

    float r[NK][8];
    #pragma unroll
    for (int k = 0; k < NK; ++k) {
        const float* pp = P + (size_t)(((k*4 + rr)*9 + s))*4096 + o;
        #pragma unroll
        for (int q = 0; q < 8; ++q)
            r[k][q] = pp[(c8 + q)*64];
    }
    #pragma unroll
    for (int b = 0; b < BATCH; ++b) {
        const float cf0 = coeffs[b*NK+0], cf1 = coeffs[b*NK+1];
        const float cf2 = coeffs[b*NK+2], cf3 = coeffs[b*NK+3];
        s16x8 w;
        #pragma unroll
        for (int q = 0; q < 8; ++q) {
            float v = cf0*r[0][q] + cf1*r[1][q] + cf2*r[2][q] + cf3*r[3][q];
            w[q] = (short)f2bf(v);
        }
        *(s16x8*)(Wb + ((((size_t)(b*9 + s)*32 + cig)*256 + co) << 3)) = w;
    }
}

// ------- kernel 4: MFMA conv (per-tap phases, double-B, setprio) ------------
// 1024 blocks, 128 threads (2 waves). block: 128 co x (2 rows x 64 px);
// wave: 64 co x 128 px. LDS [264 pix][32 ci] (contiguous 1KB wave reads).
// LDS caps occupancy (4 blocks/CU, 2 waves/SIMD) -> VGPR free to ~250:
// per tap, ALL 8 B-frags of tap s+1 batched into the alternate 32-reg buffer
// (load-to-use = 32 MFMAs ~620cyc); setprio(1) wraps the pure-MFMA cluster
// (reads outside the window; co-resident SIMD waves are from other blocks).
#define CHUNK_U 1056     // 4 rows * 66 px (16B units)
#define BUF_U   1088     // + clamp slack
#define MF(A_, B_, C_) __builtin_amdgcn_mfma_f32_16x16x32_bf16(A_, B_, C_, 0, 0, 0)

__global__ __launch_bounds__(128, 2) void conv_mfma(
        const unsigned short* __restrict__ xTg,
        const unsigned short* __restrict__ Wb,
        float* __restrict__ out) {
    const int bid  = blockIdx.x;
    const int xcd  = bid & 7;
    const int sub  = bid >> 3;         // 0..127 within this XCD
    const int b    = xcd*2 + (sub >> 6);        // batch-serial per XCD
    const int rest = sub & 63;         // 0..63
    const int coT  = rest & 1;         // 128-co half
    const int r0   = (rest >> 1) * 2;  // output row tile

    const int t    = threadIdx.x;      // 0..127
    const int w    = t >> 6;           // wave -> 64-co half within coT's 128
    const int lane = t & 63;
    const int lo16 = lane & 15;
    const int hi4  = lane >> 4;

    __shared__ __align__(16) unsigned short Xs[2*BUF_U*8];

    f32x4 acc[4][8];                   // [co-frag][px-frag]
    #pragma unroll
    for (int f = 0; f < 4; ++f)
        #pragma unroll
        for (int p = 0; p < 8; ++p)
            acc[f][p] = (f32x4)0.f;

    // per-lane W base; (s,ch) offset = (s*32 + ch*4)*2048 elements
    const unsigned short* Wlane = Wb +
        (((size_t)(b*9*32) + hi4)*256 + coT*128 + w*64 + lo16)*8;

#define LOADA(DST, CH, S)                                                       \
    do {                                                                        \
        const unsigned short* wp = Wlane + (size_t)((S)*32 + (CH)*4)*2048;      \
        _Pragma("unroll")                                                       \
        for (int f_ = 0; f_ < 4; ++f_)                                          \
            DST[f_] = *(const s16x8*)(wp + f_*128);                             \
    } while (0)

#define STAGE(CH, BUF)                                                          \
    do {                                                                        \
        const unsigned short* srcb = xTg +                                      \
            (((size_t)(b*8 + (CH)))*NPIX + r0*HP)*32;                           \
        _Pragma("unroll")                                                       \
        for (int it = 0; it < 9; ++it) {                                        \
            int ubase = it*128 + w*64;                                          \
            if (ubase < CHUNK_U) {                                              \
                int u  = ubase + lane;                                          \
                int us = u > (CHUNK_U-1) ? (CHUNK_U-1) : u;  /* src in-bounds */\
                __builtin_amdgcn_global_load_lds(                               \
                    (const GLOBAL_AS void*)(srcb + (size_t)us*8),               \
                    (LDS_AS void*)(Xs + (size_t)((BUF)*BUF_U + ubase)*8),       \
                    16, 0, 0);                                                  \
            }                                                                   \
        }                                                                       \
    } while (0)

// B-fragment LDS byte offset for flat step j (tap = j>>3, p = j&7)
#define BPIX(J) (((((J)&7)>>2) + (((J)>>3)/3))*HP + (((J)>>3)%3) + (((J)&7)&3)*16)

// batch-read all 8 B-fragments of tap S into DST
#define RDB(DST, S)                                                             \
    do {                                                                        \
        _Pragma("unroll")                                                       \
        for (int q_ = 0; q_ < 8; ++q_)                                          \
            DST[q_] = *(const s16x8*)(Xb + BPIX((S)*8 + q_)*64);                \
    } while (0)

// one tap-phase: issue next tap's B-reads + rolling A, then prioritized MFMAs
#define TAP(BC, BN, S)                                                          \
    do {                                                                        \
        if ((S) < 8) RDB(BN, (S)+1);                                            \
        if ((S) < 7) LOADA(A[(S)+2], ch, (S)+2);                                \
        __builtin_amdgcn_s_setprio(1);                                          \
        _Pragma("unroll")                                                       \
        for (int p_ = 0; p_ < 8; ++p_) {                                        \
            acc[0][p_] = MF(A[(S)][0], BC[p_], acc[0][p_]);                     \
            acc[1][p_] = MF(A[(S)][1], BC[p_], acc[1][p_]);                     \
            acc[2][p_] = MF(A[(S)][2], BC[p_], acc[2][p_]);                     \
            acc[3][p_] = MF(A[(S)][3], BC[p_], acc[3][p_]);                     \
        }                                                                       \
        __builtin_amdgcn_s_setprio(0);                                          \
    } while (0)

    STAGE(0, 0);
    __syncthreads();

    for (int ch = 0; ch < 8; ++ch) {
        s16x8 A[9][4];
        LOADA(A[0], ch, 0);
        LOADA(A[1], ch, 1);
        __builtin_amdgcn_sched_barrier(0);   // keep A[0..1] ahead of staging
        if (ch < 7) STAGE(ch+1, (ch+1) & 1);

        // per-lane LDS base: pixel lane (lo16) * 64B + ci-group (hi4) * 16B
        const char* Xb = (const char*)Xs + (ch & 1)*(BUF_U*16)
                         + lo16*64 + hi4*16;

        s16x8 B0[8], B1[8];
        RDB(B0, 0);                          // prologue: tap 0
        TAP(B0, B1, 0);
        TAP(B1, B0, 1);
        TAP(B0, B1, 2);
        TAP(B1, B0, 3);
        TAP(B0, B1, 4);
        TAP(B1, B0, 5);
        TAP(B0, B1, 6);
        TAP(B1, B0, 7);
        TAP(B0, B1, 8);
        __syncthreads();   // buffer swap; staging (issued at chunk top) long done
    }
#undef TAP
#undef RDB
#undef BPIX
#undef STAGE
#undef LOADA

    // ---- epilogue: D row = co (hi4*4+j), col = pixel (lo16) ----
    #pragma unroll
    for (int f = 0; f < 4; ++f)
        #pragma unroll
        for (int p = 0; p < 8; ++p) {
            const int row  = r0 + (p >> 2);
            const int colb = (p & 3)*16 + lo16;
            #pragma unroll
            for (int j = 0; j < 4; ++j) {
                int co = coT*128 + w*64 + f*16 + hi4*4 + j;
                out[(((size_t)(b*CT + co))*HW + row)*HW + colb] = acc[f][p][j];
            }
        }
}

extern "C" void kernel_launch(void* const* d_in, const int* in_sizes, int n_in,
                              void* d_out, int out_size, void* d_ws, size_t ws_size,
                              hipStream_t stream) {
    const float* x    = (const float*)d_in[0];
    const float* bank = (const float*)d_in[1];
    const float* fc_w = (const float*)d_in[2];
    const float* fc_b = (const float*)d_in[3];
    float* out = (float*)d_out;

    // workspace layout (bytes)
    //   partial  : 0        .. 1048576   (16*64*256 f32)
    //   bankRotP : 1048576  .. 3407872   (589824 f32)
    //   coeffs   : 3407872  .. 3408128   (64 f32)
    //   Wb       : 3408384  .. 22282752  (9437184 bf16)
    //   xTg2     : 22282752 .. 57967104  (17842176 bf16)
    char* wsb = (char*)d_ws;
    float* partial = (float*)wsb;
    float* Prot    = (float*)(wsb + 1048576);
    float* coeffs  = (float*)(wsb + 3407872);
    unsigned short* Wb  = (unsigned short*)(wsb + 3408384);
    unsigned short* xTg = (unsigned short*)(wsb + 22282752);

    xpose_pool<<<dim3(4, HP, BATCH), 256, 0, stream>>>(x, xTg, partial);
    coeff_bankrot_kernel<<<80, 256, 0, stream>>>(partial, fc_w, fc_b, bank,
                                                 coeffs, Prot);
    wbuild_kernel<<<dim3(32, 9), 256, 0, stream>>>(coeffs, Prot, Wb);
    conv_mfma<<<1024, 128, 0, stream>>>(xTg, Wb, out);
}

// Round 18
// 90.324 us; speedup vs baseline: 1.0194x; 1.0194x over previous
//
#include <hip/hip_runtime.h>
#include <hip/hip_bf16.h>
#include <math.h>

#define BATCH 16
#define CT    256   // total input channels = R*Cin
#define HW    64
#define OCH   64    // O
#define NK    4     // K kernels in bank
#define HP    66    // padded spatial
#define NPIX  4356  // 66*66

typedef __attribute__((ext_vector_type(4)))  float  f32x4;
typedef __attribute__((ext_vector_type(8)))  short  s16x8;
typedef __attribute__((ext_vector_type(4)))  unsigned short u16x4;

#define GLOBAL_AS __attribute__((address_space(1)))
#define LDS_AS    __attribute__((address_space(3)))

// rot90 source-index tables: w[s] = base[rotsrc[k][s]]
__device__ __constant__ int c_rotsrc[4][9] = {
    {0,1,2,3,4,5,6,7,8},
    {2,5,8,1,4,7,0,3,6},
    {8,7,6,5,4,3,2,1,0},
    {6,3,0,7,4,1,8,5,2}
};

static __device__ inline unsigned short f2bf(float f) {
    union { __hip_bfloat16 h; unsigned short u; } cv;
    cv.h = __float2bfloat16(f);
    return cv.u;
}

// ---------------- kernel 1: fused transpose+pad+pool-partials ----------------
// xTg2[b][ch(8)][pix(4356)][32ci] bf16, zero borders; partial[b][r][ci] sums.
__global__ __launch_bounds__(256) void xpose_pool(const float* __restrict__ x,
                                                  unsigned short* __restrict__ xTg,
                                                  float* __restrict__ partial) {
    const int ci0 = blockIdx.x * 64;
    const int ch0 = ci0 >> 5;          // first of 2 chunks
    const int pr  = blockIdx.y;        // padded row 0..65
    const int b   = blockIdx.z;
    const int t   = threadIdx.x;

    if (pr == 0 || pr == HP-1) {       // zero top/bottom padded rows
        for (int u = t; u < 528; u += 256) {   // 2ch x 66px x 4 quads
            int chl = (u >= 264) ? 1 : 0;
            int rem = u - chl*264;
            int c = rem >> 2, q = rem & 3;
            *(s16x8*)(xTg + (((size_t)(b*8 + ch0 + chl))*NPIX + pr*HP + c)*32 + q*8) =
                (s16x8)(short)0;
        }
        return;
    }
    const int r = pr - 1;

    __shared__ unsigned short tile[64][70];
    const int cilH = t >> 4;        // 0..15
    const int c0   = (t & 15) * 4;  // col group
    #pragma unroll
    for (int i = 0; i < 4; ++i) {
        int cil = cilH + i*16;
        f32x4 v = *(const f32x4*)(x + (((size_t)(b*CT + ci0 + cil))*HW + r)*HW + c0);
        tile[cil][c0+0] = f2bf(v[0]);
        tile[cil][c0+1] = f2bf(v[1]);
        tile[cil][c0+2] = f2bf(v[2]);
        tile[cil][c0+3] = f2bf(v[3]);
        float s = v[0] + v[1] + v[2] + v[3];
        s += __shfl_xor(s, 1, 16);
        s += __shfl_xor(s, 2, 16);
        s += __shfl_xor(s, 4, 16);
        s += __shfl_xor(s, 8, 16);
        if ((t & 15) == 0)
            partial[((size_t)(b*HW) + r)*CT + ci0 + cil] = s;
    }
    __syncthreads();

    if (t < 16) {                      // zero left/right border pixels
        int side = t >> 3, r8 = t & 7;
        int chl = r8 >> 2, q = r8 & 3;
        *(s16x8*)(xTg + (((size_t)(b*8 + ch0 + chl))*NPIX + pr*HP + side*(HP-1))*32 + q*8) =
            (s16x8)(short)0;
    }
    // transposed interior writes: ci-innermost, fully coalesced 64B runs
    #pragma unroll
    for (int i = 0; i < 4; ++i) {
        const int chl = i >> 1;
        const int c   = (i & 1)*32 + (t >> 3);   // 0..63
        const int q   = t & 7;                   // ci quad within chunk
        u16x4 w;
        w[0] = tile[chl*32 + q*4 + 0][c];
        w[1] = tile[chl*32 + q*4 + 1][c];
        w[2] = tile[chl*32 + q*4 + 2][c];
        w[3] = tile[chl*32 + q*4 + 3][c];
        *(u16x4*)(xTg + (((size_t)(b*8 + ch0 + chl))*NPIX + pr*HP + c + 1)*32 + q*4) = w;
    }
}

// ------- kernel 2: fused (coeff reduce+FC+sigmoid) | (bank rotation) --------
__global__ __launch_bounds__(256) void coeff_bankrot_kernel(
        const float* __restrict__ partial,
        const float* __restrict__ fc_w,
        const float* __restrict__ fc_b,
        const float* __restrict__ bank,
        float* __restrict__ coeffs,
        float* __restrict__ P) {
    const int blk = blockIdx.x;
    const int t   = threadIdx.x;

    if (blk < BATCH) {                 // ---- coeff part ----
        const int b = blk;
        const float* pp = partial + (size_t)b*HW*CT + t;
        float s = 0.f;
        #pragma unroll 8
        for (int r = 0; r < HW; ++r) s += pp[(size_t)r*CT];
        __shared__ float pool[CT];
        pool[t] = s * (1.f / (HW*HW));
        __syncthreads();
        const int w = t >> 6, l = t & 63;
        float d = 0.f;
        for (int c = l; c < CT; c += 64) d += pool[c] * fc_w[w*CT + c];
        for (int off = 32; off; off >>= 1) d += __shfl_down(d, off, 64);
        if (l == 0)
            coeffs[b*NK + w] = 1.f / (1.f + expf(-(d + fc_b[w])));
        return;
    }

    // ---- bankrot part: idx over 4*64*64 ----
    const int idx = (blk - BATCH) * 256 + t;
    const int o = idx & 63;
    const int c = (idx >> 6) & 63;
    const int k = idx >> 12;
    const float* bp = bank + ((size_t)((k*OCH + o)*64 + c))*9;
    float v[9];
    #pragma unroll
    for (int s = 0; s < 9; ++s) v[s] = bp[s];
    #pragma unroll
    for (int rr = 0; rr < 4; ++rr)
        #pragma unroll
        for (int s = 0; s < 9; ++s)
            P[(size_t)(((k*4 + rr)*9 + s))*4096 + c*64 + o] = v[c_rotsrc[rr][s]];
}

// ---------------- kernel 3: coalesced mix -> bf16 weights ----------------
// W[b][s][cig][co][8ci]; grid (32 cig, 9 s) x 256 threads (co).
__global__ __launch_bounds__(256) void wbuild_kernel(const float* __restrict__ coeffs,
                                                     const float* __restrict__ P,
                                                     unsigned short* __restrict__ Wb) {
    const int cig = blockIdx.x;
    const int s   = blockIdx.y;
    const int co  = threadIdx.x;
    const int ro  = co >> 6;
    const int o   = co & 63;
    const int ri  = cig >> 3;
    const int rr  = (ro - ri) & 3;
    const int c8  = (cig & 7) * 8;

    float r[NK][8];
    #pragma unroll
    for (int k = 0; k < NK; ++k) {
        const float* pp = P + (size_t)(((k*4 + rr)*9 + s))*4096 + o;
        #pragma unroll
        for (int q = 0; q < 8; ++q)
            r[k][q] = pp[(c8 + q)*64];
    }
    #pragma unroll
    for (int b = 0; b < BATCH; ++b) {
        const float cf0 = coeffs[b*NK+0], cf1 = coeffs[b*NK+1];
        const float cf2 = coeffs[b*NK+2], cf3 = coeffs[b*NK+3];
        s16x8 w;
        #pragma unroll
        for (int q = 0; q < 8; ++q) {
            float v = cf0*r[0][q] + cf1*r[1][q] + cf2*r[2][q] + cf3*r[3][q];
            w[q] = (short)f2bf(v);
        }
        *(s16x8*)(Wb + ((((size_t)(b*9 + s)*32 + cig)*256 + co) << 3)) = w;
    }
}

// ------- kernel 4: MFMA conv (72-step pipeline + batch-serial XCD map) ------
// 1024 blocks, 128 threads (2 waves). block: 128 co x (2 rows x 64 px);
// wave: 64 co x 128 px. LDS [264 pix][32 ci] (contiguous 1KB wave reads).
// Inner loop: 72 flat (tap,p) steps, rotating 4-slot bfw window, load-to-use
// = 16 MFMAs; depth-2 rolling A prefetch; A[0..1] issued before STAGE
// (in-order vmcnt: counted A-waits never drain the staging burst).
#define CHUNK_U 1056     // 4 rows * 66 px (16B units)
#define BUF_U   1088     // + clamp slack
#define MF(A_, B_, C_) __builtin_amdgcn_mfma_f32_16x16x32_bf16(A_, B_, C_, 0, 0, 0)

__global__ __launch_bounds__(128, 2) void conv_mfma(
        const unsigned short* __restrict__ xTg,
        const unsigned short* __restrict__ Wb,
        float* __restrict__ out) {
    const int bid  = blockIdx.x;
    const int xcd  = bid & 7;
    const int sub  = bid >> 3;         // 0..127 within this XCD
    const int b    = xcd*2 + (sub >> 6);        // batch-serial per XCD
    const int rest = sub & 63;         // 0..63
    const int coT  = rest & 1;         // 128-co half
    const int r0   = (rest >> 1) * 2;  // output row tile

    const int t    = threadIdx.x;      // 0..127
    const int w    = t >> 6;           // wave -> 64-co half within coT's 128
    const int lane = t & 63;
    const int lo16 = lane & 15;
    const int hi4  = lane >> 4;

    __shared__ __align__(16) unsigned short Xs[2*BUF_U*8];

    f32x4 acc[4][8];                   // [co-frag][px-frag]
    #pragma unroll
    for (int f = 0; f < 4; ++f)
        #pragma unroll
        for (int p = 0; p < 8; ++p)
            acc[f][p] = (f32x4)0.f;

    // per-lane W base; (s,ch) offset = (s*32 + ch*4)*2048 elements
    const unsigned short* Wlane = Wb +
        (((size_t)(b*9*32) + hi4)*256 + coT*128 + w*64 + lo16)*8;

#define LOADA(DST, CH, S)                                                       \
    do {                                                                        \
        const unsigned short* wp = Wlane + (size_t)((S)*32 + (CH)*4)*2048;      \
        _Pragma("unroll")                                                       \
        for (int f_ = 0; f_ < 4; ++f_)                                          \
            DST[f_] = *(const s16x8*)(wp + f_*128);                             \
    } while (0)

#define STAGE(CH, BUF)                                                          \
    do {                                                                        \
        const unsigned short* srcb = xTg +                                      \
            (((size_t)(b*8 + (CH)))*NPIX + r0*HP)*32;                           \
        _Pragma("unroll")                                                       \
        for (int it = 0; it < 9; ++it) {                                        \
            int ubase = it*128 + w*64;                                          \
            if (ubase < CHUNK_U) {                                              \
                int u  = ubase + lane;                                          \
                int us = u > (CHUNK_U-1) ? (CHUNK_U-1) : u;  /* src in-bounds */\
                __builtin_amdgcn_global_load_lds(                               \
                    (const GLOBAL_AS void*)(srcb + (size_t)us*8),               \
                    (LDS_AS void*)(Xs + (size_t)((BUF)*BUF_U + ubase)*8),       \
                    16, 0, 0);                                                  \
            }                                                                   \
        }                                                                       \
    } while (0)

// B-fragment LDS byte offset for flat step j (tap = j>>3, p = j&7)
#define BPIX(J) (((((J)&7)>>2) + (((J)>>3)/3))*HP + (((J)>>3)%3) + (((J)&7)&3)*16)

    STAGE(0, 0);
    __syncthreads();

    for (int ch = 0; ch < 8; ++ch) {
        s16x8 A[9][4];
        LOADA(A[0], ch, 0);
        LOADA(A[1], ch, 1);
        __builtin_amdgcn_sched_barrier(0);   // keep A[0..1] ahead of staging
        if (ch < 7) STAGE(ch+1, (ch+1) & 1);

        // per-lane LDS base: pixel lane (lo16) * 64B + ci-group (hi4) * 16B
        const char* Xb = (const char*)Xs + (ch & 1)*(BUF_U*16)
                         + lo16*64 + hi4*16;

        // prologue: first 4 B-fragments (tap 0, p=0..3)
        s16x8 bfw[4];
        #pragma unroll
        for (int i = 0; i < 4; ++i)
            bfw[i] = *(const s16x8*)(Xb + BPIX(i)*64);

        #pragma unroll
        for (int i = 0; i < 72; ++i) {
            const int s = i >> 3, p = i & 7;
            if (p == 0 && s < 7) LOADA(A[s+2], ch, s+2);  // depth-2 rolling A
            // compute on the fragment loaded 4 steps ago
            acc[0][p] = MF(A[s][0], bfw[i & 3], acc[0][p]);
            acc[1][p] = MF(A[s][1], bfw[i & 3], acc[1][p]);
            acc[2][p] = MF(A[s][2], bfw[i & 3], acc[2][p]);
            acc[3][p] = MF(A[s][3], bfw[i & 3], acc[3][p]);
            // issue the read for step i+4 into the now-dead slot
            if (i < 68)
                bfw[(i + 4) & 3] = *(const s16x8*)(Xb + BPIX(i + 4)*64);
        }
        __syncthreads();   // buffer swap; staging (issued at chunk top) long done
    }
#undef BPIX
#undef STAGE
#undef LOADA

    // ---- epilogue: D row = co (hi4*4+j), col = pixel (lo16) ----
    #pragma unroll
    for (int f = 0; f < 4; ++f)
        #pragma unroll
        for (int p = 0; p < 8; ++p) {
            const int row  = r0 + (p >> 2);
            const int colb = (p & 3)*16 + lo16;
            #pragma unroll
            for (int j = 0; j < 4; ++j) {
                int co = coT*128 + w*64 + f*16 + hi4*4 + j;
                out[(((size_t)(b*CT + co))*HW + row)*HW + colb] = acc[f][p][j];
            }
        }
}

extern "C" void kernel_launch(void* const* d_in, const int* in_sizes, int n_in,
                              void* d_out, int out_size, void* d_ws, size_t ws_size,
                              hipStream_t stream) {
    const float* x    = (const float*)d_in[0];
    const float* bank = (const float*)d_in[1];
    const float* fc_w = (const float*)d_in[2];
    const float* fc_b = (const float*)d_in[3];
    float* out = (float*)d_out;

    // workspace layout (bytes)
    //   partial  : 0        .. 1048576   (16*64*256 f32)
    //   bankRotP : 1048576  .. 3407872   (589824 f32)
    //   coeffs   : 3407872  .. 3408128   (64 f32)
    //   Wb       : 3408384  .. 22282752  (9437184 bf16)
    //   xTg2     : 22282752 .. 57967104  (17842176 bf16)
    char* wsb = (char*)d_ws;
    float* partial = (float*)wsb;
    float* Prot    = (float*)(wsb + 1048576);
    float* coeffs  = (float*)(wsb + 3407872);
    unsigned short* Wb  = (unsigned short*)(wsb + 3408384);
    unsigned short* xTg = (unsigned short*)(wsb + 22282752);

    xpose_pool<<<dim3(4, HP, BATCH), 256, 0, stream>>>(x, xTg, partial);
    coeff_bankrot_kernel<<<80, 256, 0, stream>>>(partial, fc_w, fc_b, bank,
                                                 coeffs, Prot);
    wbuild_kernel<<<dim3(32, 9), 256, 0, stream>>>(coeffs, Prot, Wb);
    conv_mfma<<<1024, 128, 0, stream>>>(xTg, Wb, out);
}